// Round 1
// baseline (2449.964 us; speedup 1.0000x reference)
//
#include <hip/hip_runtime.h>

#define BN_EPS 1e-5f
constexpr int C = 256;
constexpr int B = 128;

// Generic 3x3 VALID conv + inference BN + ReLU.
// Block = 256 threads = PT position-threads x CT co-threads (CT = 256/PT).
// Each thread: O output channels x P positions accumulated in registers.
// Per chunk: stage CCH input channels + CO_TILE x CCH x 9 weights in LDS.
template<int HIN, int WIN, int PT, int O, int CCH>
__global__ __launch_bounds__(256) void conv3_bn_relu(
    const float* __restrict__ in, const float* __restrict__ w,
    const float* __restrict__ gamma, const float* __restrict__ beta,
    const float* __restrict__ mean, const float* __restrict__ var,
    float* __restrict__ out)
{
    constexpr int HOUT = HIN - 2, WOUT = WIN - 2;
    constexpr int NPOS = HOUT * WOUT;
    constexpr int HW = HIN * WIN;
    constexpr int CT = 256 / PT;
    constexpr int CO_TILE = CT * O;
    constexpr int P = (NPOS + PT - 1) / PT;
    constexpr int NCHUNK = C / CCH;

    __shared__ float s_in[CCH * HW];
    __shared__ float s_w[CO_TILE * CCH * 9];

    const int t = threadIdx.x;
    const int pos_t = t % PT;
    const int co_t = t / PT;

    const int b = blockIdx.x;
    const int co0 = blockIdx.y * CO_TILE;

    int base_off[P];
    bool valid[P];
#pragma unroll
    for (int j = 0; j < P; ++j) {
        int pos = pos_t + j * PT;
        valid[j] = pos < NPOS;
        int pp = valid[j] ? pos : 0;
        int y = pp / WOUT, x = pp - y * WOUT;
        base_off[j] = y * WIN + x;
    }

    float acc[O][P];
#pragma unroll
    for (int i = 0; i < O; ++i)
#pragma unroll
        for (int j = 0; j < P; ++j) acc[i][j] = 0.f;

    const float* in_b = in + (size_t)b * C * HW;

    for (int ch = 0; ch < NCHUNK; ++ch) {
        const int c0 = ch * CCH;
        __syncthreads();
        // stage input channels [c0, c0+CCH)
        for (int idx = t; idx < CCH * HW; idx += 256)
            s_in[idx] = in_b[(size_t)c0 * HW + idx];
        // stage weights: LDS idx = ol*(CCH*9) + cc*9 + k
        for (int idx = t; idx < CO_TILE * CCH * 9; idx += 256) {
            int ol = idx / (CCH * 9);
            int rem = idx - ol * (CCH * 9);
            s_w[idx] = w[(size_t)(co0 + ol) * C * 9 + (size_t)c0 * 9 + rem];
        }
        __syncthreads();

#pragma unroll
        for (int cc = 0; cc < CCH; ++cc) {
#pragma unroll
            for (int k = 0; k < 9; ++k) {
                const int dy = k / 3, dx = k - dy * 3;
                float wv[O];
#pragma unroll
                for (int i = 0; i < O; ++i)
                    wv[i] = s_w[(co_t * O + i) * (CCH * 9) + cc * 9 + k];
                float iv[P];
#pragma unroll
                for (int j = 0; j < P; ++j)
                    iv[j] = s_in[cc * HW + base_off[j] + dy * WIN + dx];
#pragma unroll
                for (int i = 0; i < O; ++i)
#pragma unroll
                    for (int j = 0; j < P; ++j)
                        acc[i][j] += wv[i] * iv[j];
            }
        }
    }

#pragma unroll
    for (int i = 0; i < O; ++i) {
        const int co = co0 + co_t * O + i;
        const float sc = gamma[co] * rsqrtf(var[co] + BN_EPS);
        const float sh = beta[co] - mean[co] * sc;
        float* outp = out + ((size_t)b * C + co) * NPOS;
#pragma unroll
        for (int j = 0; j < P; ++j) {
            if (valid[j]) {
                float v = acc[i][j] * sc + sh;
                outp[pos_t + j * PT] = v > 0.f ? v : 0.f;
            }
        }
    }
}

// Depthwise 5x5 valid cross-correlation: one block per (b,c) plane.
__global__ __launch_bounds__(256) void xcorr_dw(
    const float* __restrict__ s, const float* __restrict__ k,
    float* __restrict__ out)
{
    const int bc = blockIdx.x;
    const float* sp = s + (size_t)bc * 841;
    const float* kp = k + (size_t)bc * 25;
    float* op = out + (size_t)bc * 625;

    __shared__ float s_s[841];
    __shared__ float s_k[25];
    const int t = threadIdx.x;
    for (int i = t; i < 841; i += 256) s_s[i] = sp[i];
    if (t < 25) s_k[t] = kp[t];
    __syncthreads();

    float kk[25];
#pragma unroll
    for (int i = 0; i < 25; ++i) kk[i] = s_k[i];

#pragma unroll
    for (int j = 0; j < 3; ++j) {
        int pos = t + j * 256;
        if (pos < 625) {
            int y = pos / 25, x = pos - y * 25;
            float a = 0.f;
#pragma unroll
            for (int dy = 0; dy < 5; ++dy)
#pragma unroll
                for (int dx = 0; dx < 5; ++dx)
                    a += s_s[(y + dy) * 29 + x + dx] * kk[dy * 5 + dx];
            op[pos] = a;
        }
    }
}

extern "C" void kernel_launch(void* const* d_in, const int* in_sizes, int n_in,
                              void* d_out, int out_size, void* d_ws, size_t ws_size,
                              hipStream_t stream) {
    const float* kin = (const float*)d_in[0];   // [128,256,7,7]
    const float* sin_ = (const float*)d_in[1];  // [128,256,31,31]
    const float* wk = (const float*)d_in[2];    // [256,256,3,3]
    const float* bkg = (const float*)d_in[3];
    const float* bkb = (const float*)d_in[4];
    const float* bkm = (const float*)d_in[5];
    const float* bkv = (const float*)d_in[6];
    const float* ws_ = (const float*)d_in[7];   // [256,256,3,3]
    const float* bsg = (const float*)d_in[8];
    const float* bsb = (const float*)d_in[9];
    const float* bsm = (const float*)d_in[10];
    const float* bsv = (const float*)d_in[11];
    float* out = (float*)d_out;

    // workspace layout: k [128*256*25] then s [128*256*841] floats
    float* kbuf = (float*)d_ws;
    float* sbuf = kbuf + (size_t)B * C * 25;

    // kernel conv: 7x7 -> 5x5. PT=32 (25 pos), O=8 -> CO_TILE=64.
    conv3_bn_relu<7, 7, 32, 8, 8>
        <<<dim3(B, C / 64), 256, 0, stream>>>(kin, wk, bkg, bkb, bkm, bkv, kbuf);

    // search conv: 31x31 -> 29x29. PT=256, O=16 -> CO_TILE=16.
    conv3_bn_relu<31, 31, 256, 16, 8>
        <<<dim3(B, C / 16), 256, 0, stream>>>(sin_, ws_, bsg, bsb, bsm, bsv, sbuf);

    // depthwise xcorr: s [B,C,29,29] x k [B,C,5,5] -> out [B,C,25,25]
    xcorr_dw<<<B * C, 256, 0, stream>>>(sbuf, kbuf, out);
}

// Round 2
// 379.909 us; speedup vs baseline: 6.4488x; 6.4488x over previous
//
#include <hip/hip_runtime.h>
#include <hip/hip_bf16.h>

#define BN_EPS 1e-5f
constexpr int C = 256;
constexpr int B = 128;

typedef __attribute__((ext_vector_type(8))) short bf16x8;
typedef __attribute__((ext_vector_type(4))) float f32x4;

static __device__ __forceinline__ unsigned short f2bf(float f) {
    __hip_bfloat16 h = __float2bfloat16(f);
    return *reinterpret_cast<unsigned short*>(&h);
}
static __device__ __forceinline__ float bf2f(unsigned short u) {
    unsigned int v = ((unsigned int)u) << 16;
    return __uint_as_float(v);
}

// Fold BN scale into weights, transpose [N][C][9] f32 -> [9][N][C] bf16.
__global__ __launch_bounds__(256) void wprep(
    const float* __restrict__ w, const float* __restrict__ gamma,
    const float* __restrict__ var, unsigned short* __restrict__ wt)
{
    const int n = blockIdx.x, c = threadIdx.x;
    const float scale = gamma[n] * rsqrtf(var[n] + BN_EPS);
    const float* wp = w + ((size_t)n * C + c) * 9;
#pragma unroll
    for (int k = 0; k < 9; ++k)
        wt[((size_t)k * C + n) * C + c] = f2bf(wp[k] * scale);
}

// Implicit-GEMM 3x3 VALID conv + BN(folded scale)+bias + ReLU via bf16 MFMA.
// Input NCHW fp32; weights [9][N][C] bf16 (pre-scaled); output NCHW (padded plane).
// Block: 256 thr = 4 waves (2x2). Wave tile (MF*16) x (NF*16). K chunked by 32 ch.
template<int HIN, int WOUT, int BPB, int BM, int BN_, int MF, int NF, bool OUT_BF16, int OSTRIDE>
__global__ __launch_bounds__(256) void conv3_mfma(
    const float* __restrict__ in, const unsigned short* __restrict__ wt,
    const float* __restrict__ gamma, const float* __restrict__ beta,
    const float* __restrict__ mean, const float* __restrict__ var,
    void* __restrict__ outv)
{
    constexpr int WIN = HIN;
    constexpr int NPOS = WOUT * WOUT;
    constexpr int PPB = BM / BPB;                 // positions per batch in tile
    constexpr int NMT = (NPOS + PPB - 1) / PPB;
    constexpr int CCH = 32;
    constexpr int NCH = C / CCH;
    constexpr int NR0 = (PPB - 1) / WOUT + 4;     // out rows spanned + 2 halo + 1
    constexpr int NROWS = NR0 < HIN ? NR0 : HIN;
    constexpr int APIX = NROWS * WIN;
    constexpr int LDK = 40;                        // padded k-dim (80B stride)

    __shared__ __align__(16) short s_a[BPB * APIX * LDK];
    __shared__ __align__(16) short s_w[3 * BN_ * LDK];

    const int t = threadIdx.x;
    const int lane = t & 63;
    const int wave = t >> 6;
    const int wm = wave >> 1, wn = wave & 1;
    const int lr = lane >> 4, lc = lane & 15;

    const int mt = blockIdx.x % NMT;
    const int nt = blockIdx.x / NMT;
    const int p0 = mt * PPB;
    const int n0 = nt * BN_;
    const int b0 = blockIdx.y * BPB;
    const int y0 = p0 / WOUT;
    const int R = (HIN - y0) < NROWS ? (HIN - y0) : NROWS;
    const int npix = R * WIN;

    // A-fragment row bases (pixel row index in staged window, dy=dx=0)
    int arow[MF];
#pragma unroll
    for (int m = 0; m < MF; ++m) {
        int pm = wm * MF * 16 + m * 16 + lc;
        int bb = pm / PPB;
        int p = p0 + (pm % PPB);
        p = p < NPOS ? p : NPOS - 1;
        int y = p / WOUT, x = p % WOUT;
        arow[m] = bb * APIX + (y - y0) * WIN + x;
    }

    f32x4 acc[MF][NF];
#pragma unroll
    for (int m = 0; m < MF; ++m)
#pragma unroll
        for (int n = 0; n < NF; ++n) acc[m][n] = f32x4{0.f, 0.f, 0.f, 0.f};

    const int cc = t >> 3;        // staging channel (0..31)
    const int slot = t & 7;       // staging pixel-quad slot

    for (int ch = 0; ch < NCH; ++ch) {
        const int c0 = ch * CCH;
        __syncthreads();
        // ---- stage A: [pixels][32ch] transposed, bf16 ----
#pragma unroll
        for (int bb = 0; bb < BPB; ++bb) {
            const float* src = in + ((size_t)(b0 + bb) * C + c0 + cc) * (HIN * WIN) + y0 * WIN;
            short* dstb = &s_a[(size_t)bb * APIX * LDK + cc];
            for (int px = slot * 4; px < npix; px += 32) {
                if (px + 4 <= npix) {
                    float a0 = src[px], a1 = src[px + 1], a2 = src[px + 2], a3 = src[px + 3];
                    dstb[(px + 0) * LDK] = (short)f2bf(a0);
                    dstb[(px + 1) * LDK] = (short)f2bf(a1);
                    dstb[(px + 2) * LDK] = (short)f2bf(a2);
                    dstb[(px + 3) * LDK] = (short)f2bf(a3);
                } else {
#pragma unroll
                    for (int j = 0; j < 4; ++j)
                        if (px + j < npix) dstb[(px + j) * LDK] = (short)f2bf(src[px + j]);
                }
            }
        }

#pragma unroll 1
        for (int dy = 0; dy < 3; ++dy) {
            if (dy) __syncthreads();
            // ---- stage B: 3 offsets x BN_ x 32ch ----
            for (int i = t; i < 3 * BN_ * 4; i += 256) {
                int part = i & 3;
                int row = i >> 2;              // off*BN_ + n
                int off = row / BN_;
                int n = row % BN_;
                const unsigned short* sp =
                    wt + ((size_t)(dy * 3 + off) * C + (n0 + n)) * C + c0 + part * 8;
                bf16x8 v = *(const bf16x8*)sp;
                *(bf16x8*)&s_w[row * LDK + part * 8] = v;
            }
            __syncthreads();

#pragma unroll
            for (int dx = 0; dx < 3; ++dx) {
                bf16x8 af[MF], bfr[NF];
#pragma unroll
                for (int m = 0; m < MF; ++m) {
                    int row = arow[m] + dy * WIN + dx;
                    af[m] = *(const bf16x8*)&s_a[row * LDK + lr * 8];
                }
#pragma unroll
                for (int n = 0; n < NF; ++n) {
                    int wrow = dx * BN_ + wn * NF * 16 + n * 16 + lc;
                    bfr[n] = *(const bf16x8*)&s_w[wrow * LDK + lr * 8];
                }
#pragma unroll
                for (int m = 0; m < MF; ++m)
#pragma unroll
                    for (int n = 0; n < NF; ++n)
                        acc[m][n] = __builtin_amdgcn_mfma_f32_16x16x32_bf16(
                            af[m], bfr[n], acc[m][n], 0, 0, 0);
            }
        }
    }

    // ---- epilogue: bias + relu, write NCHW (padded plane stride OSTRIDE) ----
#pragma unroll
    for (int n = 0; n < NF; ++n) {
        const int co = n0 + wn * NF * 16 + n * 16 + lc;
        const float sc = gamma[co] * rsqrtf(var[co] + BN_EPS);
        const float bias = beta[co] - mean[co] * sc;
#pragma unroll
        for (int m = 0; m < MF; ++m) {
            int pm = wm * MF * 16 + m * 16 + lr * 4;
            int bb = pm / PPB;
            int p = p0 + (pm % PPB);
            int b = b0 + bb;
            f32x4 v = acc[m][n];
            float r0 = fmaxf(v.x + bias, 0.f);
            float r1 = fmaxf(v.y + bias, 0.f);
            float r2 = fmaxf(v.z + bias, 0.f);
            float r3 = fmaxf(v.w + bias, 0.f);
            if (OUT_BF16) {
                unsigned short* op = (unsigned short*)outv + ((size_t)b * C + co) * OSTRIDE + p;
                if (p + 4 <= NPOS) {
                    ushort4 pk;
                    pk.x = f2bf(r0); pk.y = f2bf(r1); pk.z = f2bf(r2); pk.w = f2bf(r3);
                    *(ushort4*)op = pk;
                } else {
                    float rr[4] = {r0, r1, r2, r3};
#pragma unroll
                    for (int i = 0; i < 4; ++i)
                        if (p + i < NPOS) op[i] = f2bf(rr[i]);
                }
            } else {
                float* op = (float*)outv + ((size_t)b * C + co) * OSTRIDE + p;
                float rr[4] = {r0, r1, r2, r3};
#pragma unroll
                for (int i = 0; i < 4; ++i)
                    if (p + i < NPOS) op[i] = rr[i];
            }
        }
    }
}

// Depthwise 5x5 valid xcorr: s bf16 [B,C,844-padded 29x29], k f32 [B,C,28-padded 5x5].
__global__ __launch_bounds__(256) void xcorr_dw(
    const unsigned short* __restrict__ s, const float* __restrict__ k,
    float* __restrict__ out)
{
    const int bc = blockIdx.x;
    const unsigned short* sp = s + (size_t)bc * 844;
    const float* kp = k + (size_t)bc * 28;
    float* op = out + (size_t)bc * 625;

    __shared__ float s_s[841];
    __shared__ float s_k[25];
    const int t = threadIdx.x;
    for (int i = t; i < 841; i += 256) s_s[i] = bf2f(sp[i]);
    if (t < 25) s_k[t] = kp[t];
    __syncthreads();

    float kk[25];
#pragma unroll
    for (int i = 0; i < 25; ++i) kk[i] = s_k[i];

#pragma unroll
    for (int j = 0; j < 3; ++j) {
        int pos = t + j * 256;
        if (pos < 625) {
            int y = pos / 25, x = pos - y * 25;
            float a = 0.f;
#pragma unroll
            for (int dy = 0; dy < 5; ++dy)
#pragma unroll
                for (int dx = 0; dx < 5; ++dx)
                    a += s_s[(y + dy) * 29 + x + dx] * kk[dy * 5 + dx];
            op[pos] = a;
        }
    }
}

extern "C" void kernel_launch(void* const* d_in, const int* in_sizes, int n_in,
                              void* d_out, int out_size, void* d_ws, size_t ws_size,
                              hipStream_t stream) {
    const float* kin = (const float*)d_in[0];   // [128,256,7,7]
    const float* sin_ = (const float*)d_in[1];  // [128,256,31,31]
    const float* wk = (const float*)d_in[2];    // [256,256,3,3]
    const float* bkg = (const float*)d_in[3];
    const float* bkb = (const float*)d_in[4];
    const float* bkm = (const float*)d_in[5];
    const float* bkv = (const float*)d_in[6];
    const float* ws_ = (const float*)d_in[7];   // [256,256,3,3]
    const float* bsg = (const float*)d_in[8];
    const float* bsb = (const float*)d_in[9];
    const float* bsm = (const float*)d_in[10];
    const float* bsv = (const float*)d_in[11];
    float* out = (float*)d_out;

    // workspace layout (bytes):
    //   sbuf bf16 [B][C][844]   : 55,312,384
    //   kbuf f32  [B][C][28]    :  3,670,016
    //   wkt  bf16 [9][256][256] :  1,179,648
    //   wst  bf16 [9][256][256] :  1,179,648
    char* base = (char*)d_ws;
    unsigned short* sbuf = (unsigned short*)base;
    float* kbuf = (float*)(base + 55312384);
    unsigned short* wkt = (unsigned short*)(base + 55312384 + 3670016);
    unsigned short* wst = wkt + (size_t)9 * C * C;

    wprep<<<C, 256, 0, stream>>>(wk, bkg, bkv, wkt);
    wprep<<<C, 256, 0, stream>>>(ws_, bsg, bsv, wst);

    // kernel conv: 7x7 -> 5x5 (M=25/batch). BPB=2, BM=64, BN=128, MF=2, NF=4, f32 out.
    conv3_mfma<7, 5, 2, 64, 128, 2, 4, false, 28>
        <<<dim3(2, B / 2), 256, 0, stream>>>(kin, wkt, bkg, bkb, bkm, bkv, kbuf);

    // search conv: 31x31 -> 29x29 (M=841/batch). BPB=1, BM=128, BN=128, MF=4, NF=4, bf16 out.
    conv3_mfma<31, 29, 1, 128, 128, 4, 4, true, 844>
        <<<dim3(14, B), 256, 0, stream>>>(sin_, wst, bsg, bsb, bsm, bsv, sbuf);

    // depthwise xcorr
    xcorr_dw<<<B * C, 256, 0, stream>>>(sbuf, kbuf, out);
}